// Round 4
// baseline (333.509 us; speedup 1.0000x reference)
//
#include <hip/hip_runtime.h>
#include <hip/hip_bf16.h>
#include <math.h>

// Cosine attention, n=8, L=S=2048, d=v=64.
// out0 = softmax((q^·k^T)/8) @ V  [8,2048,64]; out1 = softmax scores [8,2048,2048]
// |score| <= 1/8 (unit vectors) -> exp in [0.88,1.13] -> no running max needed.
// Structure = round-3 kernel (single pass, transposed QK, LDS E-exchange PV with
// 16x16x32 mfma, bf16 stash -> direct score epilogue, 1-bit mask), plus:
//   - XCD pinning: blockIdx%8 = batch n -> K[n]+Vt[n] (4 MB) resident in that
//     XCD's private 4 MB L2 (grid was x-major over l before: every XCD touched
//     all 8 batches = 32 MB working set -> L2 thrash -> L3-latency loads).
//   - non-temporal score/value stores: the 128 MB P stream no longer evicts K/Vt.
//   - single fused prep kernel (ballot-based bit-pack, no LDS; norm; Vt) ->
//     2 launches total instead of 4.
// Mask arrives as int32 (harness materializes bool as int) — NOT bytes.

typedef __bf16 bf16x8 __attribute__((ext_vector_type(8)));
typedef __bf16 bf16x4 __attribute__((ext_vector_type(4)));
typedef float f32x4 __attribute__((ext_vector_type(4)));

#define NB 8
#define LL 2048
#define SS 2048
#define DD 64
#define MWORDS 64      // SS/32 bit-words per row
#define PM_BLOCKS 2048 // mask-pack blocks in fused prep
#define NORM_BLOCKS ((NB * LL * 2) / 4)
#define VT_BLOCKS (NB * (SS / 64))

// ---- fused prep: [0,2048) mask bit-pack | [2048,10240) Q/K norm | [10240,10496) V transpose ----
__global__ __launch_bounds__(256) void prep_all(const float* __restrict__ q,
                                                const float* __restrict__ k,
                                                const float* __restrict__ v,
                                                const int* __restrict__ mask,
                                                __bf16* __restrict__ Qb,
                                                __bf16* __restrict__ Kb,
                                                __bf16* __restrict__ Vt,
                                                unsigned* __restrict__ Mb) {
  __shared__ __bf16 tile[64][72];  // used by the Vt branch only
  const int bid = blockIdx.x;
  const int t = threadIdx.x;

  if (bid < PM_BLOCKS) {
    // mask int32 -> 1 bit/element via wave ballot; coalesced 256B/wave/iter.
    // bit j of word w == mask element s = w*32 + j (matches attn consumption).
    const int lane = t & 63;
    const size_t total = (size_t)NB * LL * SS;
    const size_t stride = (size_t)PM_BLOCKS * 256;
    for (size_t i = (size_t)bid * 256 + t; i < total; i += stride) {
      int m = mask[i];
      unsigned long long b = __ballot(m != 0);
      if ((lane & 31) == 0) Mb[i >> 5] = (unsigned)(b >> (lane & 32));
    }
  } else if (bid < PM_BLOCKS + NORM_BLOCKS) {
    // L2-normalize Q (fold 1/8) and K rows, cast to bf16; one wave per row.
    const int nb = bid - PM_BLOCKS;
    const int w = t >> 6, lane = t & 63;
    const int r = nb * 4 + w;
    const float* src;
    __bf16* dst;
    float extra;
    if (r < NB * LL) {
      src = q + (size_t)r * DD;
      dst = Qb + (size_t)r * DD;
      extra = 0.125f;  // fold 1/sqrt(64) into Q
    } else {
      int rk = r - NB * LL;
      src = k + (size_t)rk * DD;
      dst = Kb + (size_t)rk * DD;
      extra = 1.0f;
    }
    float x = src[lane];
    float ss = x * x;
    ss += __shfl_xor(ss, 1);
    ss += __shfl_xor(ss, 2);
    ss += __shfl_xor(ss, 4);
    ss += __shfl_xor(ss, 8);
    ss += __shfl_xor(ss, 16);
    ss += __shfl_xor(ss, 32);
    float nrm = sqrtf(ss);
    float sc = extra / fmaxf(nrm, 1e-12f);
    dst[lane] = (__bf16)(x * sc);
  } else {
    // V [n][s][v] f32 -> Vt [n][v][s] bf16, 64x64 LDS tiles.
    const int vb = bid - PM_BLOCKS - NORM_BLOCKS;  // 0..255
    const int n = vb >> 5;
    const int s0 = (vb & 31) * 64;
#pragma unroll
    for (int it = 0; it < 4; ++it) {
      int idx = t + it * 256;
      int s = idx >> 4, c = idx & 15;
      float4 f = *(const float4*)(v + ((size_t)(n * SS + s0 + s)) * DD + c * 4);
      tile[s][c * 4 + 0] = (__bf16)f.x;
      tile[s][c * 4 + 1] = (__bf16)f.y;
      tile[s][c * 4 + 2] = (__bf16)f.z;
      tile[s][c * 4 + 3] = (__bf16)f.w;
    }
    __syncthreads();
#pragma unroll
    for (int it = 0; it < 4; ++it) {
      int idx = t + it * 256;
      int vv = idx >> 4, c = idx & 15;
      bf16x4 o;
      o[0] = tile[c * 4 + 0][vv];
      o[1] = tile[c * 4 + 1][vv];
      o[2] = tile[c * 4 + 2][vv];
      o[3] = tile[c * 4 + 3][vv];
      *(bf16x4*)(Vt + ((size_t)(n * DD + vv)) * SS + s0 + c * 4) = o;
    }
  }
}

// ---- main: 16 L-rows per block, 8 waves (512 thr), S streamed in 128-col chunks ----
// Wave w: QK for s-cols [w*16, w*16+16) of each chunk (transposed D[s][l]);
// PV split by (v-group = w&3, s-half = (w>>2)*64); end: pairwise acc reduce in LDS.
// Per-lane ownership after transposed QK: (l = l0+m16, s = sc + w*16 + quad*4 + r).
__global__ __launch_bounds__(512, 4) void attn_main(const __bf16* __restrict__ Qb,
                                                    const __bf16* __restrict__ Kb,
                                                    const __bf16* __restrict__ Vt,
                                                    const unsigned* __restrict__ Mb,
                                                    float* __restrict__ out_val,
                                                    float* __restrict__ out_score) {
  __shared__ __bf16 e_lds[2][16][136];   // E chunk, row = l (0..15), col = s-in-chunk
  __shared__ float rs_lds[8][16];        // per-wave row-sum partials
  __shared__ float acc_red[4][16][17];   // PV partial exchange (upper s-half waves)

  // XCD pinning: id%8 = XCD = batch n -> K[n]+Vt[n] stay in that XCD's L2.
  const int id = blockIdx.x;
  const int n = id & 7;
  const int l0 = (id >> 3) * 16;

  const int t = threadIdx.x;
  const int w = t >> 6;
  const int lane = t & 63;
  const int m16 = lane & 15;
  const int quad = lane >> 4;
  const int vg = w & 3;            // PV v-group
  const int sh = (w >> 2) * 64;    // PV s-half within chunk

  // Q fragment (B operand of transposed QK): B[n=m16][k=quad*8+j] = Q[l0+m16][k]
  const __bf16* qrow = Qb + ((size_t)(n * LL + l0 + m16)) * DD;
  bf16x8 aq0 = *(const bf16x8*)(qrow + quad * 8);
  bf16x8 aq1 = *(const bf16x8*)(qrow + 32 + quad * 8);

  const __bf16* kbase = Kb + (size_t)n * SS * DD;
  const __bf16* vrow = Vt + ((size_t)(n * DD + vg * 16 + m16)) * SS + sh;
  // per-lane index into out_score: row l = l0+m16, col base = w*16+quad*4
  const size_t mrow = ((size_t)(n * LL + l0 + m16)) * SS + w * 16 + quad * 4;
  // bitmask: word for this lane's 4 s-bits of chunk c is mbits[c*4]
  const int off16 = w * 16 + quad * 4;
  const unsigned* mbits = Mb + ((size_t)(n * LL + l0 + m16)) * MWORDS + (off16 >> 5);
  const int bitoff = off16 & 31;

  f32x4 acc_o = {0.f, 0.f, 0.f, 0.f};
  float rsum = 0.f;
  bf16x4 stash[16];  // exp'd scores, 4 consecutive s per chunk (static idx -> regs)
  // bit-word prefetch, depth 4 (static names; rotation resolved at unroll time)
  unsigned bw0 = mbits[0];
  unsigned bw1 = mbits[4];
  unsigned bw2 = mbits[8];
  unsigned bw3 = mbits[12];

#pragma unroll
  for (int c = 0; c < 16; ++c) {
    const int sc = c * 128;
    const int scol = sc + w * 16 + m16;
    // K fragment (A operand): A[m=m16][k] = K[sc + w*16 + m16][k]
    const __bf16* krow = kbase + (size_t)scol * DD;
    bf16x8 kb0 = *(const bf16x8*)(krow + quad * 8);
    bf16x8 kb1 = *(const bf16x8*)(krow + 32 + quad * 8);
    // Vt frags for this chunk's PV, issued early (consumed after the barrier)
    bf16x8 bv0 = *(const bf16x8*)(vrow + sc + quad * 8);
    bf16x8 bv1 = *(const bf16x8*)(vrow + sc + 32 + quad * 8);
    // QK transposed: D[row=quad*4+r -> s][col=m16 -> l]
    f32x4 acc = {0.f, 0.f, 0.f, 0.f};
    acc = __builtin_amdgcn_mfma_f32_16x16x32_bf16(kb0, aq0, acc, 0, 0, 0);
    acc = __builtin_amdgcn_mfma_f32_16x16x32_bf16(kb1, aq1, acc, 0, 0, 0);
    // bitmask word for this chunk (+ refill 4 ahead); unrolled -> static select
    unsigned bits;
    switch (c & 3) {
      case 0: bits = bw0; if (c + 4 < 16) bw0 = mbits[(c + 4) * 4]; break;
      case 1: bits = bw1; if (c + 4 < 16) bw1 = mbits[(c + 4) * 4]; break;
      case 2: bits = bw2; if (c + 4 < 16) bw2 = mbits[(c + 4) * 4]; break;
      default: bits = bw3; if (c + 4 < 16) bw3 = mbits[(c + 4) * 4]; break;
    }
    const unsigned b4 = (bits >> bitoff) & 0xFu;
    float e0 = (b4 & 1u) ? __expf(acc[0]) : 0.f;
    float e1 = (b4 & 2u) ? __expf(acc[1]) : 0.f;
    float e2 = (b4 & 4u) ? __expf(acc[2]) : 0.f;
    float e3 = (b4 & 8u) ? __expf(acc[3]) : 0.f;
    rsum += (e0 + e1) + (e2 + e3);
    bf16x4 sv;
    sv[0] = (__bf16)e0;
    sv[1] = (__bf16)e1;
    sv[2] = (__bf16)e2;
    sv[3] = (__bf16)e3;
    stash[c] = sv;
    *(bf16x4*)(&e_lds[c & 1][m16][w * 16 + quad * 4]) = sv;
    __syncthreads();
    // PV: A = E[l][s-half], B = Vt[v-group][s-half]
    bf16x8 ae0 = *(const bf16x8*)(&e_lds[c & 1][m16][sh + quad * 8]);
    bf16x8 ae1 = *(const bf16x8*)(&e_lds[c & 1][m16][sh + 32 + quad * 8]);
    acc_o = __builtin_amdgcn_mfma_f32_16x16x32_bf16(ae0, bv0, acc_o, 0, 0, 0);
    acc_o = __builtin_amdgcn_mfma_f32_16x16x32_bf16(ae1, bv1, acc_o, 0, 0, 0);
    // dbuf proof: e_lds[c&1] next written at chunk c+2, which is after barrier
    // c+1, which is after all reads of chunk c.
  }

  // rowsum: lane has partial for row l=m16 over its s slices; reduce quads, waves
  rsum += __shfl_xor(rsum, 16);
  rsum += __shfl_xor(rsum, 32);
  if (quad == 0) rs_lds[w][m16] = rsum;
  // upper s-half waves publish PV partials
  if (w >= 4) {
#pragma unroll
    for (int r = 0; r < 4; ++r) acc_red[vg][quad * 4 + r][m16] = acc_o[r];
  }
  __syncthreads();

  float tot = 0.f;
#pragma unroll
  for (int ww = 0; ww < 8; ++ww) tot += rs_lds[ww][m16];
  const float inv_s = 1.0f / tot;  // for score rows (l = l0+m16)

  // out_value: lower s-half waves combine pair partials; C/D rows are l=quad*4+r
  if (w < 4) {
#pragma unroll
    for (int r = 0; r < 4; ++r) {
      const int row = quad * 4 + r;
      float tr = 0.f;
#pragma unroll
      for (int ww = 0; ww < 8; ++ww) tr += rs_lds[ww][row];
      const float o = (acc_o[r] + acc_red[vg][row][m16]) / tr;
      __builtin_nontemporal_store(
          o, out_val + ((size_t)(n * LL + l0 + row)) * DD + vg * 16 + m16);
    }
  }

  // score epilogue: replay stash * inv, coalesced non-temporal float4 stores
  // (the only P write; nt keeps the 128 MB stream from evicting K/Vt in L2)
  float* orow = out_score + mrow;
#pragma unroll
  for (int c = 0; c < 16; ++c) {
    f32x4 o;
    o[0] = (float)stash[c][0] * inv_s;
    o[1] = (float)stash[c][1] * inv_s;
    o[2] = (float)stash[c][2] * inv_s;
    o[3] = (float)stash[c][3] * inv_s;
    __builtin_nontemporal_store(o, (f32x4*)(orow + (size_t)c * 128));
  }
}

extern "C" void kernel_launch(void* const* d_in, const int* in_sizes, int n_in,
                              void* d_out, int out_size, void* d_ws, size_t ws_size,
                              hipStream_t stream) {
  const float* q = (const float*)d_in[0];
  const float* k = (const float*)d_in[1];
  const float* v = (const float*)d_in[2];
  const int* mask = (const int*)d_in[3];  // harness materializes bool as int32

  float* out_val = (float*)d_out;                       // [8,2048,64]
  float* out_score = out_val + (size_t)NB * LL * DD;    // [8,2048,2048]

  __bf16* Qb = (__bf16*)d_ws;                  // 2 MB
  __bf16* Kb = Qb + (size_t)NB * LL * DD;      // 2 MB
  __bf16* Vt = Kb + (size_t)NB * SS * DD;      // 2 MB (transposed [n][v][s])
  unsigned* Mb = (unsigned*)(Vt + (size_t)NB * DD * SS);  // 4 MB bitmask

  prep_all<<<dim3(PM_BLOCKS + NORM_BLOCKS + VT_BLOCKS), dim3(256), 0, stream>>>(
      q, k, v, mask, Qb, Kb, Vt, Mb);
  attn_main<<<dim3((LL / 16) * NB), dim3(512), 0, stream>>>(Qb, Kb, Vt, Mb, out_val, out_score);
}